// Round 2
// baseline (1182.021 us; speedup 1.0000x reference)
//
#include <hip/hip_runtime.h>

typedef unsigned short u16;
typedef unsigned int   u32;
using bf16x8 = __attribute__((ext_vector_type(8))) __bf16;
using f32x4  = __attribute__((ext_vector_type(4))) float;

// B=2, S=2048, D=4096, H=32, KV=8, HD=128 hardcoded throughout.

__device__ __forceinline__ u16 f2bf(float f) {
  u32 u = __builtin_bit_cast(u32, f);
  return (u16)((u + 0x7fffu + ((u >> 16) & 1u)) >> 16);
}
__device__ __forceinline__ float bf2f(u16 h) {
  return __builtin_bit_cast(float, (u32)h << 16);
}
__device__ __forceinline__ f32x4 mfma16(bf16x8 a, bf16x8 b, f32x4 c) {
  return __builtin_amdgcn_mfma_f32_16x16x32_bf16(a, b, c, 0, 0, 0);
}
__device__ __forceinline__ void g2l16(const void* gp, void* lp) {
  __builtin_amdgcn_global_load_lds(
      (__attribute__((address_space(1))) void*)(void*)gp,
      (__attribute__((address_space(3))) void*)lp, 16, 0, 0);
}

// ---------------- fp32 -> bf16 elementwise ----------------
__global__ void k_cvt(const float* __restrict__ in, u16* __restrict__ out, int n4) {
  int i = blockIdx.x * 256 + threadIdx.x;
  if (i >= n4) return;
  float4 v = ((const float4*)in)[i];
  ushort4 o;
  o.x = f2bf(v.x); o.y = f2bf(v.y); o.z = f2bf(v.z); o.w = f2bf(v.w);
  ((ushort4*)out)[i] = o;
}

// ---------------- fp32 (K,N) -> bf16 (N,K) transpose-convert ----------------
__global__ void k_tcvt(const float* __restrict__ in, u16* __restrict__ out, int K, int N) {
  __shared__ u16 t[32][33];
  int n0 = blockIdx.x * 32, k0 = blockIdx.y * 32;
  int r = threadIdx.x >> 3, c4 = (threadIdx.x & 7) * 4;
  float4 v = *(const float4*)(in + (size_t)(k0 + r) * N + n0 + c4);
  t[c4 + 0][r] = f2bf(v.x);
  t[c4 + 1][r] = f2bf(v.y);
  t[c4 + 2][r] = f2bf(v.z);
  t[c4 + 3][r] = f2bf(v.w);
  __syncthreads();
  ushort4 o;
  o.x = t[r][c4 + 0]; o.y = t[r][c4 + 1]; o.z = t[r][c4 + 2]; o.w = t[r][c4 + 3];
  *(ushort4*)(out + (size_t)(n0 + r) * K + k0 + c4) = o;
}

// ---------------- 128x128x32 bf16 GEMM (m97 structure) ----------------
// A: (M,K) bf16 row-major.  Bt: (N,K) bf16 row-major (pre-transposed).
// MODE 1: bf16 out relayout (b, NH, s, d), row=(b,s) col=(h,d)
// MODE 2: fp32 out plain row-major
// MODE 3: bf16 out 4-way split (K0|K1|V0|V1), each (b,8,s,d)
template <int MODE>
__global__ __launch_bounds__(256) void k_gemm(const u16* __restrict__ A, const u16* __restrict__ Bt,
                                              void* __restrict__ Cp, int M, int N, int K, int NH) {
  __shared__ u16 As[128 * 32];
  __shared__ u16 Bs[128 * 32];
  const int m0 = blockIdx.y * 128, n0 = blockIdx.x * 128;
  const int tid = threadIdx.x, wid = tid >> 6, l = tid & 63, g = l >> 4, li = l & 15;
  const int rb = (wid >> 1) * 64, cb = (wid & 1) * 64;
  const f32x4 vzero = {0.f, 0.f, 0.f, 0.f};
  f32x4 acc[4][4];
  for (int m = 0; m < 4; ++m)
    for (int n = 0; n < 4; ++n) acc[m][n] = vzero;
  const int srow = l >> 2, scol = (l & 3) * 8;  // staging: 8KB tile = 8 chunks of 1KB
  for (int k0 = 0; k0 < K; k0 += 32) {
#pragma unroll
    for (int i = 0; i < 2; ++i) {
      int c = wid * 2 + i;
      g2l16(A + (size_t)(m0 + c * 16 + srow) * K + k0 + scol, As + c * 512);
      g2l16(Bt + (size_t)(n0 + c * 16 + srow) * K + k0 + scol, Bs + c * 512);
    }
    __syncthreads();
    bf16x8 af[4], bf[4];
#pragma unroll
    for (int m = 0; m < 4; ++m) af[m] = *(const bf16x8*)(As + (rb + m * 16 + li) * 32 + g * 8);
#pragma unroll
    for (int n = 0; n < 4; ++n) bf[n] = *(const bf16x8*)(Bs + (cb + n * 16 + li) * 32 + g * 8);
#pragma unroll
    for (int m = 0; m < 4; ++m)
#pragma unroll
      for (int n = 0; n < 4; ++n)
        acc[m][n] = mfma16(af[m], bf[n], acc[m][n]);
    __syncthreads();
  }
  (void)NH;
#pragma unroll
  for (int m = 0; m < 4; ++m)
#pragma unroll
    for (int n = 0; n < 4; ++n)
#pragma unroll
      for (int j = 0; j < 4; ++j) {
        int row = m0 + rb + m * 16 + g * 4 + j;   // C/D: row=(l>>4)*4+reg
        int col = n0 + cb + n * 16 + li;          //      col=l&15
        float v = acc[m][n][j];
        if constexpr (MODE == 2) {
          ((float*)Cp)[(size_t)row * N + col] = v;
        } else if constexpr (MODE == 1) {
          int b = row >> 11, s = row & 2047, h = col >> 7, d = col & 127;
          ((u16*)Cp)[(((size_t)(b * NH + h)) * 2048 + s) * 128 + d] = f2bf(v);
        } else {
          int b = row >> 11, s = row & 2047;
          int buf = col >> 10, hh = (col >> 7) & 7, d = col & 127;
          ((u16*)Cp)[(size_t)buf * 4194304 + (((size_t)(b * 8 + hh)) * 2048 + s) * 128 + d] = f2bf(v);
        }
      }
}

// ---------------- RoPE on Q in place, fused 1/sqrt(128) scale ----------------
// Qr layout (b,h,s,d); one wave per row; lane l handles pair (d=l, d=l+64).
__global__ void k_ropeq(u16* __restrict__ Q, const int* __restrict__ pos) {
  int row = blockIdx.x * 4 + (threadIdx.x >> 6);
  int l = threadIdx.x & 63;
  int s = row & 2047;
  u16* p = Q + (size_t)row * 128;
  float x1 = bf2f(p[l]), x2 = bf2f(p[l + 64]);
  float ang = (float)pos[s] * expf((float)l * -0.14391156831212787f);  // ln(1e4)/64
  float cs = cosf(ang), sn = sinf(ang);
  const float sc = 0.08838834764831845f;  // 1/sqrt(128)
  p[l] = f2bf((x1 * cs - x2 * sn) * sc);
  p[l + 64] = f2bf((x2 * cs + x1 * sn) * sc);
}

// ---------------- K/V: modality select + RoPE(K) + V transpose to (d,s) ----------------
// block = (b, kv, 64-token tile); K0..V1 are (b,8,s,d) bf16.
__global__ void k_kvprep(const u16* __restrict__ K0, const u16* __restrict__ K1,
                         const u16* __restrict__ V0, const u16* __restrict__ V1,
                         const int* __restrict__ mod, const int* __restrict__ pos,
                         u16* __restrict__ Kr, u16* __restrict__ Vt) {
  __shared__ u16 Vl[64][136];
  int blk = blockIdx.x;
  int st = blk & 31, kvh = (blk >> 5) & 7, b = blk >> 8;
  int s0 = st * 64;
  int tid = threadIdx.x, wid = tid >> 6, l = tid & 63;
  float invf = expf((float)l * -0.14391156831212787f);
  size_t slab = (size_t)(b * 8 + kvh) * 2048;
  for (int rr = 0; rr < 16; ++rr) {
    int r = wid * 16 + rr;
    int s = s0 + r;
    int sel = mod[b * 2048 + s];
    const u16* ks = (sel ? K1 : K0) + (slab + s) * 128;
    const u16* vs = (sel ? V1 : V0) + (slab + s) * 128;
    float ang = (float)pos[s] * invf;
    float cs = cosf(ang), sn = sinf(ang);
    float x1 = bf2f(ks[l]), x2 = bf2f(ks[l + 64]);
    u16* kd = Kr + (slab + s) * 128;
    kd[l] = f2bf(x1 * cs - x2 * sn);
    kd[l + 64] = f2bf(x2 * cs + x1 * sn);
    Vl[r][l] = vs[l];
    Vl[r][l + 64] = vs[l + 64];
  }
  __syncthreads();
  int d = tid >> 1, si0 = (tid & 1) * 32;
  u16* vd = Vt + ((size_t)(b * 8 + kvh) * 128 + d) * 2048 + s0 + si0;
#pragma unroll
  for (int k4 = 0; k4 < 8; ++k4) {
    ushort4 o;
    o.x = Vl[si0 + k4 * 4 + 0][d];
    o.y = Vl[si0 + k4 * 4 + 1][d];
    o.z = Vl[si0 + k4 * 4 + 2][d];
    o.w = Vl[si0 + k4 * 4 + 3][d];
    *(ushort4*)(vd + k4 * 4) = o;
  }
}

// ---------------- causal GQA flash attention (barrier-free) ----------------
// grid (16, B*H): block handles q-tile pair {qt, 31-qt} (uniform 33 kt-tiles).
// 4 waves x 16 q-rows. K/V MFMA fragments loaded DIRECTLY from global
// (L1/L2-resident: K+V per (b,kvh) = 1MB, reused by 4 heads x all q-tiles).
// LDS holds only per-wave P (no __syncthreads anywhere in the kt loop).
__global__ __launch_bounds__(256, 3) void k_attn(const u16* __restrict__ Q, const u16* __restrict__ Kr,
                                                 const u16* __restrict__ Vt, u16* __restrict__ ctx) {
  __shared__ __bf16 Pl[4][16 * 68];
  const int pair = blockIdx.x, bh = blockIdx.y;
  const int b = bh >> 5, h = bh & 31, kvh = h >> 2;
  const int tid = threadIdx.x, wid = tid >> 6, l = tid & 63, g = l >> 4, li = l & 15;
  const size_t kvslab = (size_t)(b * 8 + kvh) * 2048;
  const u16* Kg = Kr + kvslab * 128;
  const u16* Vg = Vt + kvslab * 128;  // (d, s) layout
  // hoisted fragment base pointers (bake lane offsets in)
  const char* kb[4];
#pragma unroll
  for (int cf = 0; cf < 4; ++cf)
    kb[cf] = (const char*)Kg + ((cf * 16 + li) * 128 + g * 8) * 2;
  const char* vb[8];
#pragma unroll
  for (int db = 0; db < 8; ++db)
    vb[db] = (const char*)Vg + ((size_t)(db * 16 + li) * 2048 + g * 8) * 2;
  __bf16* Pw = &Pl[wid][0];

  for (int half = 0; half < 2; ++half) {
    const int qt = half ? (31 - pair) : pair;
    const int q0 = qt * 64;
    // Q fragments (already RoPE'd + scaled): A-map (l,j) -> row=li, k=g*8+j
    const u16* qrow = Q + ((size_t)bh * 2048 + q0 + wid * 16 + li) * 128;
    bf16x8 qf[4];
#pragma unroll
    for (int ks = 0; ks < 4; ++ks) qf[ks] = *(const bf16x8*)(qrow + ks * 32 + g * 8);
    const f32x4 vzero = {0.f, 0.f, 0.f, 0.f};
    f32x4 o[8];
#pragma unroll
    for (int i = 0; i < 8; ++i) o[i] = vzero;
    float mrow[4] = {-1e30f, -1e30f, -1e30f, -1e30f};
    float lsum[4] = {0.f, 0.f, 0.f, 0.f};

    for (int kt = 0; kt <= qt; ++kt) {
      const int koff = kt * 16384;  // byte offset into K tile rows (64*128*2)
      const int voff = kt * 128;    // byte offset along V's s-dim (64*2)
      // ---- QK^T : A=Q, B=K (col = k token) ----
      f32x4 sf[4];
#pragma unroll
      for (int cf = 0; cf < 4; ++cf) sf[cf] = vzero;
#pragma unroll
      for (int ks = 0; ks < 4; ++ks) {
        bf16x8 kf[4];
#pragma unroll
        for (int cf = 0; cf < 4; ++cf)
          kf[cf] = *(const bf16x8*)(kb[cf] + koff + ks * 64);
        __builtin_amdgcn_s_setprio(1);
#pragma unroll
        for (int cf = 0; cf < 4; ++cf) sf[cf] = mfma16(qf[ks], kf[cf], sf[cf]);
        __builtin_amdgcn_s_setprio(0);
      }
      if (kt == qt) {  // diagonal tile causal mask
#pragma unroll
        for (int cf = 0; cf < 4; ++cf)
#pragma unroll
          for (int j = 0; j < 4; ++j) {
            if (cf * 16 + li > wid * 16 + g * 4 + j) sf[cf][j] = -1e30f;
          }
      }
      // ---- online softmax (scores pre-scaled via Q) ----
      float resc[4];
#pragma unroll
      for (int j = 0; j < 4; ++j) {
        float mx = fmaxf(fmaxf(sf[0][j], sf[1][j]), fmaxf(sf[2][j], sf[3][j]));
#pragma unroll
        for (int dl = 1; dl < 16; dl <<= 1) mx = fmaxf(mx, __shfl_xor(mx, dl));
        float nm = fmaxf(mrow[j], mx);
        resc[j] = exp2f((mrow[j] - nm) * 1.4426950408889634f);
        mrow[j] = nm;
        float rs = 0.f;
#pragma unroll
        for (int cf = 0; cf < 4; ++cf) {
          float p = exp2f((sf[cf][j] - nm) * 1.4426950408889634f);
          sf[cf][j] = p;
          rs += p;
        }
#pragma unroll
        for (int dl = 1; dl < 16; dl <<= 1) rs += __shfl_xor(rs, dl);
        lsum[j] = lsum[j] * resc[j] + rs;
      }
#pragma unroll
      for (int db = 0; db < 8; ++db)
#pragma unroll
        for (int j = 0; j < 4; ++j) o[db][j] *= resc[j];
      // ---- P -> LDS (C/D layout in, A layout out; stride 68 = conflict-free) ----
#pragma unroll
      for (int cf = 0; cf < 4; ++cf)
#pragma unroll
        for (int j = 0; j < 4; ++j)
          Pw[(g * 4 + j) * 68 + cf * 16 + li] = (__bf16)sf[cf][j];
      // ---- PV : A=P, B=V^T (col = d), V direct from global ----
#pragma unroll
      for (int ks = 0; ks < 2; ++ks) {
        bf16x8 pa = *(const bf16x8*)(Pw + li * 68 + ks * 32 + g * 8);
        bf16x8 vf[8];
#pragma unroll
        for (int db = 0; db < 8; ++db)
          vf[db] = *(const bf16x8*)(vb[db] + voff + ks * 64);
        __builtin_amdgcn_s_setprio(1);
#pragma unroll
        for (int db = 0; db < 8; ++db) o[db] = mfma16(pa, vf[db], o[db]);
        __builtin_amdgcn_s_setprio(0);
      }
    }
    // epilogue: normalize, write ctx (b, s, h*128+d) bf16
    float inv[4];
#pragma unroll
    for (int j = 0; j < 4; ++j) inv[j] = 1.0f / lsum[j];
#pragma unroll
    for (int db = 0; db < 8; ++db)
#pragma unroll
      for (int j = 0; j < 4; ++j) {
        int row = q0 + wid * 16 + g * 4 + j;
        ctx[((size_t)(b * 2048) + row) * 4096 + h * 128 + db * 16 + li] = f2bf(o[db][j] * inv[j]);
      }
  }
}

extern "C" void kernel_launch(void* const* d_in, const int* in_sizes, int n_in,
                              void* d_out, int out_size, void* d_ws, size_t ws_size,
                              hipStream_t stream) {
  (void)in_sizes; (void)n_in; (void)out_size; (void)ws_size;
  const float* X   = (const float*)d_in[0];
  const int*   mod = (const int*)d_in[1];
  const int*   pos = (const int*)d_in[2];
  const float* Wq  = (const float*)d_in[3];
  const float* Wk0 = (const float*)d_in[4];
  const float* Wk1 = (const float*)d_in[5];
  const float* Wv0 = (const float*)d_in[6];
  const float* Wv1 = (const float*)d_in[7];
  const float* Wo  = (const float*)d_in[8];
  float* out = (float*)d_out;

  u16* p = (u16*)d_ws;
  auto take = [&](size_t n) { u16* r = p; p += n; return r; };
  u16* Xb   = take(16777216);  // X bf16 (4096 x 4096)
  u16* WqT  = take(16777216);  // Wq^T (4096 x 4096)
  u16* WoT  = take(16777216);  // Wo^T
  u16* WkvT = take(16777216);  // [Wk0|Wk1|Wv0|Wv1]^T stacked (4096 x 4096)
  u16* Qr   = take(16777216);  // (b,h,s,d)
  u16* KV4  = take(16777216);  // K0r|K1r|V0r|V1r, each (b,8,s,d)
  // aliases (lifetimes disjoint, stream-ordered):
  u16* Kr  = WqT;               // roped+selected K (b,8,s,d)
  u16* Vtr = WqT + 4194304;     // selected V transposed (b,8,d,s)
  u16* ctx = Xb;                // attention out (b,s,h*128+d)

  k_cvt<<<dim3(16384), 256, 0, stream>>>(X, Xb, 4194304);
  k_tcvt<<<dim3(128, 128), 256, 0, stream>>>(Wq, WqT, 4096, 4096);
  k_tcvt<<<dim3(32, 128), 256, 0, stream>>>(Wk0, WkvT,               4096, 1024);
  k_tcvt<<<dim3(32, 128), 256, 0, stream>>>(Wk1, WkvT + 1 * 4194304, 4096, 1024);
  k_tcvt<<<dim3(32, 128), 256, 0, stream>>>(Wv0, WkvT + 2 * 4194304, 4096, 1024);
  k_tcvt<<<dim3(32, 128), 256, 0, stream>>>(Wv1, WkvT + 3 * 4194304, 4096, 1024);
  k_tcvt<<<dim3(128, 128), 256, 0, stream>>>(Wo, WoT, 4096, 4096);

  k_gemm<1><<<dim3(32, 32), 256, 0, stream>>>(Xb, WqT,  (void*)Qr,  4096, 4096, 4096, 32);
  k_gemm<3><<<dim3(32, 32), 256, 0, stream>>>(Xb, WkvT, (void*)KV4, 4096, 4096, 4096, 8);

  k_ropeq<<<dim3(32768), 256, 0, stream>>>(Qr, pos);
  k_kvprep<<<dim3(512), 256, 0, stream>>>(KV4, KV4 + 4194304, KV4 + 2 * 4194304,
                                          KV4 + 3 * 4194304, mod, pos, Kr, Vtr);

  k_attn<<<dim3(16, 64), 256, 0, stream>>>(Qr, Kr, Vtr, ctx);

  k_gemm<2><<<dim3(32, 32), 256, 0, stream>>>(ctx, WoT, (void*)out, 4096, 4096, 4096, 0);
}

// Round 3
// 920.725 us; speedup vs baseline: 1.2838x; 1.2838x over previous
//
#include <hip/hip_runtime.h>

typedef unsigned short u16;
typedef unsigned int   u32;
using bf16x8 = __attribute__((ext_vector_type(8))) __bf16;
using f32x4  = __attribute__((ext_vector_type(4))) float;

// B=2, S=2048, D=4096, H=32, KV=8, HD=128 hardcoded throughout.

__device__ __forceinline__ u16 f2bf(float f) {
  u32 u = __builtin_bit_cast(u32, f);
  return (u16)((u + 0x7fffu + ((u >> 16) & 1u)) >> 16);
}
__device__ __forceinline__ float bf2f(u16 h) {
  return __builtin_bit_cast(float, (u32)h << 16);
}
__device__ __forceinline__ f32x4 mfma16(bf16x8 a, bf16x8 b, f32x4 c) {
  return __builtin_amdgcn_mfma_f32_16x16x32_bf16(a, b, c, 0, 0, 0);
}
__device__ __forceinline__ void g2l16(const void* gp, void* lp) {
  __builtin_amdgcn_global_load_lds(
      (__attribute__((address_space(1))) void*)(void*)gp,
      (__attribute__((address_space(3))) void*)lp, 16, 0, 0);
}

// ---------------- fp32 -> bf16 elementwise ----------------
__global__ void k_cvt(const float* __restrict__ in, u16* __restrict__ out, int n4) {
  int i = blockIdx.x * 256 + threadIdx.x;
  if (i >= n4) return;
  float4 v = ((const float4*)in)[i];
  ushort4 o;
  o.x = f2bf(v.x); o.y = f2bf(v.y); o.z = f2bf(v.z); o.w = f2bf(v.w);
  ((ushort4*)out)[i] = o;
}

// ---------------- fp32 (K,N) -> bf16 (N,K) transpose-convert ----------------
__global__ void k_tcvt(const float* __restrict__ in, u16* __restrict__ out, int K, int N) {
  __shared__ u16 t[32][33];
  int n0 = blockIdx.x * 32, k0 = blockIdx.y * 32;
  int r = threadIdx.x >> 3, c4 = (threadIdx.x & 7) * 4;
  float4 v = *(const float4*)(in + (size_t)(k0 + r) * N + n0 + c4);
  t[c4 + 0][r] = f2bf(v.x);
  t[c4 + 1][r] = f2bf(v.y);
  t[c4 + 2][r] = f2bf(v.z);
  t[c4 + 3][r] = f2bf(v.w);
  __syncthreads();
  ushort4 o;
  o.x = t[r][c4 + 0]; o.y = t[r][c4 + 1]; o.z = t[r][c4 + 2]; o.w = t[r][c4 + 3];
  *(ushort4*)(out + (size_t)(n0 + r) * K + k0 + c4) = o;
}

// ---------------- 128x128x32 bf16 GEMM (m97 structure) ----------------
// A: (M,K) bf16 row-major.  Bt: (N,K) bf16 row-major (pre-transposed).
// MODE 1: bf16 out relayout (b, NH, s, d), row=(b,s) col=(h,d)
// MODE 2: fp32 out plain row-major
// MODE 3: bf16 out 4-way split (K0|K1|V0|V1), each (b,8,s,d)
template <int MODE>
__global__ __launch_bounds__(256) void k_gemm(const u16* __restrict__ A, const u16* __restrict__ Bt,
                                              void* __restrict__ Cp, int M, int N, int K, int NH) {
  __shared__ u16 As[128 * 32];
  __shared__ u16 Bs[128 * 32];
  const int m0 = blockIdx.y * 128, n0 = blockIdx.x * 128;
  const int tid = threadIdx.x, wid = tid >> 6, l = tid & 63, g = l >> 4, li = l & 15;
  const int rb = (wid >> 1) * 64, cb = (wid & 1) * 64;
  const f32x4 vzero = {0.f, 0.f, 0.f, 0.f};
  f32x4 acc[4][4];
  for (int m = 0; m < 4; ++m)
    for (int n = 0; n < 4; ++n) acc[m][n] = vzero;
  const int srow = l >> 2, scol = (l & 3) * 8;  // staging: 8KB tile = 8 chunks of 1KB
  for (int k0 = 0; k0 < K; k0 += 32) {
#pragma unroll
    for (int i = 0; i < 2; ++i) {
      int c = wid * 2 + i;
      g2l16(A + (size_t)(m0 + c * 16 + srow) * K + k0 + scol, As + c * 512);
      g2l16(Bt + (size_t)(n0 + c * 16 + srow) * K + k0 + scol, Bs + c * 512);
    }
    __syncthreads();
    bf16x8 af[4], bf[4];
#pragma unroll
    for (int m = 0; m < 4; ++m) af[m] = *(const bf16x8*)(As + (rb + m * 16 + li) * 32 + g * 8);
#pragma unroll
    for (int n = 0; n < 4; ++n) bf[n] = *(const bf16x8*)(Bs + (cb + n * 16 + li) * 32 + g * 8);
#pragma unroll
    for (int m = 0; m < 4; ++m)
#pragma unroll
      for (int n = 0; n < 4; ++n)
        acc[m][n] = mfma16(af[m], bf[n], acc[m][n]);
    __syncthreads();
  }
  (void)NH;
#pragma unroll
  for (int m = 0; m < 4; ++m)
#pragma unroll
    for (int n = 0; n < 4; ++n)
#pragma unroll
      for (int j = 0; j < 4; ++j) {
        int row = m0 + rb + m * 16 + g * 4 + j;   // C/D: row=(l>>4)*4+reg
        int col = n0 + cb + n * 16 + li;          //      col=l&15
        float v = acc[m][n][j];
        if constexpr (MODE == 2) {
          ((float*)Cp)[(size_t)row * N + col] = v;
        } else if constexpr (MODE == 1) {
          int b = row >> 11, s = row & 2047, h = col >> 7, d = col & 127;
          ((u16*)Cp)[(((size_t)(b * NH + h)) * 2048 + s) * 128 + d] = f2bf(v);
        } else {
          int b = row >> 11, s = row & 2047;
          int buf = col >> 10, hh = (col >> 7) & 7, d = col & 127;
          ((u16*)Cp)[(size_t)buf * 4194304 + (((size_t)(b * 8 + hh)) * 2048 + s) * 128 + d] = f2bf(v);
        }
      }
}

// ---------------- RoPE on Q in place, fused 1/sqrt(128) scale ----------------
// Qr layout (b,h,s,d); one wave per row; lane l handles pair (d=l, d=l+64).
__global__ void k_ropeq(u16* __restrict__ Q, const int* __restrict__ pos) {
  int row = blockIdx.x * 4 + (threadIdx.x >> 6);
  int l = threadIdx.x & 63;
  int s = row & 2047;
  u16* p = Q + (size_t)row * 128;
  float x1 = bf2f(p[l]), x2 = bf2f(p[l + 64]);
  float ang = (float)pos[s] * expf((float)l * -0.14391156831212787f);  // ln(1e4)/64
  float cs = cosf(ang), sn = sinf(ang);
  const float sc = 0.08838834764831845f;  // 1/sqrt(128)
  p[l] = f2bf((x1 * cs - x2 * sn) * sc);
  p[l + 64] = f2bf((x2 * cs + x1 * sn) * sc);
}

// ---------------- K/V: modality select + RoPE(K) + V transpose to (d,s) ----------------
// block = (b, kv, 64-token tile); K0..V1 are (b,8,s,d) bf16.
__global__ void k_kvprep(const u16* __restrict__ K0, const u16* __restrict__ K1,
                         const u16* __restrict__ V0, const u16* __restrict__ V1,
                         const int* __restrict__ mod, const int* __restrict__ pos,
                         u16* __restrict__ Kr, u16* __restrict__ Vt) {
  __shared__ u16 Vl[64][136];
  int blk = blockIdx.x;
  int st = blk & 31, kvh = (blk >> 5) & 7, b = blk >> 8;
  int s0 = st * 64;
  int tid = threadIdx.x, wid = tid >> 6, l = tid & 63;
  float invf = expf((float)l * -0.14391156831212787f);
  size_t slab = (size_t)(b * 8 + kvh) * 2048;
  for (int rr = 0; rr < 16; ++rr) {
    int r = wid * 16 + rr;
    int s = s0 + r;
    int sel = mod[b * 2048 + s];
    const u16* ks = (sel ? K1 : K0) + (slab + s) * 128;
    const u16* vs = (sel ? V1 : V0) + (slab + s) * 128;
    float ang = (float)pos[s] * invf;
    float cs = cosf(ang), sn = sinf(ang);
    float x1 = bf2f(ks[l]), x2 = bf2f(ks[l + 64]);
    u16* kd = Kr + (slab + s) * 128;
    kd[l] = f2bf(x1 * cs - x2 * sn);
    kd[l + 64] = f2bf(x2 * cs + x1 * sn);
    Vl[r][l] = vs[l];
    Vl[r][l + 64] = vs[l + 64];
  }
  __syncthreads();
  int d = tid >> 1, si0 = (tid & 1) * 32;
  u16* vd = Vt + ((size_t)(b * 8 + kvh) * 128 + d) * 2048 + s0 + si0;
#pragma unroll
  for (int k4 = 0; k4 < 8; ++k4) {
    ushort4 o;
    o.x = Vl[si0 + k4 * 4 + 0][d];
    o.y = Vl[si0 + k4 * 4 + 1][d];
    o.z = Vl[si0 + k4 * 4 + 2][d];
    o.w = Vl[si0 + k4 * 4 + 3][d];
    *(ushort4*)(vd + k4 * 4) = o;
  }
}

// ---------------- causal GQA flash attention (double-buffered, pair-fused) ----------------
// grid (16, B*H): block fuses q-tile pair {qtA=p, qtB=31-p} in ONE kt loop
// (kt = 0..qtB; half A active while kt<=qtA) -> 26% less staging, 2x compute
// density on shared tiles, uniform block duration.
// K/V tiles double-buffered in LDS via global_load_lds (T3-minimum 2-phase:
// issue STAGE(next) BEFORE compute, ONE vmcnt-drain barrier per tile).
// K reads swizzled (inverse-swizzled source, rule #21); P pad 68 = conflict-free.
#define COMPUTE_HALF(KT, QT, QF, O, MR, LS)                                    \
  {                                                                            \
    f32x4 sf[4];                                                               \
    sf[0] = vzero; sf[1] = vzero; sf[2] = vzero; sf[3] = vzero;                \
    _Pragma("unroll")                                                          \
    for (int ks = 0; ks < 4; ++ks) {                                           \
      bf16x8 kf[4];                                                            \
      _Pragma("unroll")                                                        \
      for (int cf = 0; cf < 4; ++cf) {                                         \
        int krow = cf * 16 + li;                                               \
        int koff = (krow * 256 + ks * 64 + g * 16) ^ ((krow & 7) << 4);        \
        kf[cf] = *(const bf16x8*)(kbase + koff);                               \
      }                                                                        \
      __builtin_amdgcn_s_setprio(1);                                           \
      _Pragma("unroll")                                                        \
      for (int cf = 0; cf < 4; ++cf) sf[cf] = mfma16(QF[ks], kf[cf], sf[cf]);  \
      __builtin_amdgcn_s_setprio(0);                                           \
    }                                                                          \
    if ((KT) == (QT)) {                                                        \
      _Pragma("unroll")                                                        \
      for (int cf = 0; cf < 4; ++cf)                                           \
        _Pragma("unroll")                                                      \
        for (int j = 0; j < 4; ++j)                                            \
          if (cf * 16 + li > wid * 16 + g * 4 + j) sf[cf][j] = -1e30f;         \
    }                                                                          \
    float resc[4];                                                             \
    _Pragma("unroll")                                                          \
    for (int j = 0; j < 4; ++j) {                                              \
      float mx = fmaxf(fmaxf(sf[0][j], sf[1][j]), fmaxf(sf[2][j], sf[3][j])); \
      _Pragma("unroll")                                                        \
      for (int dl = 1; dl < 16; dl <<= 1) mx = fmaxf(mx, __shfl_xor(mx, dl)); \
      float nm = fmaxf(MR[j], mx);                                             \
      resc[j] = exp2f((MR[j] - nm) * 1.4426950408889634f);                     \
      MR[j] = nm;                                                              \
      float rs = 0.f;                                                          \
      _Pragma("unroll")                                                        \
      for (int cf = 0; cf < 4; ++cf) {                                         \
        float pv = exp2f((sf[cf][j] - nm) * 1.4426950408889634f);              \
        sf[cf][j] = pv;                                                        \
        rs += pv;                                                              \
      }                                                                        \
      _Pragma("unroll")                                                        \
      for (int dl = 1; dl < 16; dl <<= 1) rs += __shfl_xor(rs, dl);            \
      LS[j] = LS[j] * resc[j] + rs;                                            \
    }                                                                          \
    _Pragma("unroll")                                                          \
    for (int db = 0; db < 8; ++db)                                             \
      _Pragma("unroll")                                                        \
      for (int j = 0; j < 4; ++j) O[db][j] *= resc[j];                         \
    _Pragma("unroll")                                                          \
    for (int cf = 0; cf < 4; ++cf)                                             \
      _Pragma("unroll")                                                        \
      for (int j = 0; j < 4; ++j)                                              \
        Pw[(g * 4 + j) * 68 + cf * 16 + li] = (__bf16)sf[cf][j];               \
    _Pragma("unroll")                                                          \
    for (int ks = 0; ks < 2; ++ks) {                                           \
      bf16x8 pa = *(const bf16x8*)(Pw + li * 68 + ks * 32 + g * 8);            \
      bf16x8 vf[8];                                                            \
      _Pragma("unroll")                                                        \
      for (int db = 0; db < 8; ++db) {                                         \
        int vrow = db * 16 + li;                                               \
        int voff = (vrow * 128 + ks * 64 + g * 16) ^ ((vrow & 7) << 4);        \
        vf[db] = *(const bf16x8*)(vbase + voff);                               \
      }                                                                        \
      __builtin_amdgcn_s_setprio(1);                                           \
      _Pragma("unroll")                                                        \
      for (int db = 0; db < 8; ++db) O[db] = mfma16(pa, vf[db], O[db]);        \
      __builtin_amdgcn_s_setprio(0);                                           \
    }                                                                          \
  }

__global__ __launch_bounds__(256, 2) void k_attn(const u16* __restrict__ Q, const u16* __restrict__ Kr,
                                                 const u16* __restrict__ Vt, u16* __restrict__ ctx) {
  __shared__ u16 Kl[2 * 64 * 128];
  __shared__ u16 Vl[2 * 128 * 64];
  __shared__ __bf16 Pl[4][16 * 68];
  const int pair = blockIdx.x, bh = blockIdx.y;
  const int b = bh >> 5, h = bh & 31, kvh = h >> 2;
  const int tid = threadIdx.x, wid = tid >> 6, l = tid & 63, g = l >> 4, li = l & 15;
  const int qtA = pair, qtB = 31 - pair;
  const size_t kvslab = (size_t)(b * 8 + kvh) * 2048;
  const u16* Kg = Kr + kvslab * 128;
  const u16* Vg = Vt + kvslab * 128;  // (d, s) layout
  __bf16* Pw = &Pl[wid][0];

  // staging: 16 chunks x 1KB each for K and V tiles; inverse-swizzled source
  auto stage = [&](int kt, int bi) {
#pragma unroll
    for (int i = 0; i < 4; ++i) {
      int c = wid * 4 + i;
      int slot = c * 1024 + l * 16;
      {  // K tile: 64 rows x 256B
        int row = slot >> 8;
        int inner = (slot & 255) ^ ((row & 7) << 4);
        g2l16((const char*)Kg + kt * 16384 + row * 256 + inner,
              (char*)Kl + bi * 16384 + c * 1024);
      }
      {  // V tile: 128 rows x 128B (rows = d, cols = s-slice of 64 tokens)
        int row = slot >> 7;
        int inner = (slot & 127) ^ ((row & 7) << 4);
        g2l16((const char*)Vg + (size_t)row * 4096 + kt * 128 + inner,
              (char*)Vl + bi * 16384 + c * 1024);
      }
    }
  };

  // Q fragments for both halves: A-map (l,j) -> row=li, k=g*8+j
  const u16* qrowA = Q + ((size_t)bh * 2048 + qtA * 64 + wid * 16 + li) * 128;
  const u16* qrowB = Q + ((size_t)bh * 2048 + qtB * 64 + wid * 16 + li) * 128;
  bf16x8 qfA[4], qfB[4];
#pragma unroll
  for (int ks = 0; ks < 4; ++ks) {
    qfA[ks] = *(const bf16x8*)(qrowA + ks * 32 + g * 8);
    qfB[ks] = *(const bf16x8*)(qrowB + ks * 32 + g * 8);
  }
  const f32x4 vzero = {0.f, 0.f, 0.f, 0.f};
  f32x4 oA[8], oB[8];
#pragma unroll
  for (int i = 0; i < 8; ++i) { oA[i] = vzero; oB[i] = vzero; }
  float mA[4] = {-1e30f, -1e30f, -1e30f, -1e30f};
  float mB[4] = {-1e30f, -1e30f, -1e30f, -1e30f};
  float lA[4] = {0.f, 0.f, 0.f, 0.f};
  float lB[4] = {0.f, 0.f, 0.f, 0.f};

  stage(0, 0);
  __syncthreads();
  int cur = 0;
  for (int kt = 0; kt <= qtB; ++kt) {
    if (kt < qtB) stage(kt + 1, cur ^ 1);  // issue next-tile loads FIRST
    const char* kbase = (const char*)Kl + cur * 16384;
    const char* vbase = (const char*)Vl + cur * 16384;
    if (kt <= qtA) COMPUTE_HALF(kt, qtA, qfA, oA, mA, lA);
    COMPUTE_HALF(kt, qtB, qfB, oB, mB, lB);
    __syncthreads();  // drains vmcnt(0): next tile resident, this buf free
    cur ^= 1;
  }

  // epilogue: normalize, write ctx (b, s, h*128+d) bf16
#pragma unroll
  for (int half = 0; half < 2; ++half) {
    const int q0 = (half ? qtB : qtA) * 64;
    f32x4* o = half ? oB : oA;
    float* ls = half ? lB : lA;
    float inv[4];
#pragma unroll
    for (int j = 0; j < 4; ++j) inv[j] = 1.0f / ls[j];
#pragma unroll
    for (int db = 0; db < 8; ++db)
#pragma unroll
      for (int j = 0; j < 4; ++j) {
        int row = q0 + wid * 16 + g * 4 + j;
        ctx[((size_t)(b * 2048) + row) * 4096 + h * 128 + db * 16 + li] = f2bf(o[db][j] * inv[j]);
      }
  }
}

extern "C" void kernel_launch(void* const* d_in, const int* in_sizes, int n_in,
                              void* d_out, int out_size, void* d_ws, size_t ws_size,
                              hipStream_t stream) {
  (void)in_sizes; (void)n_in; (void)out_size; (void)ws_size;
  const float* X   = (const float*)d_in[0];
  const int*   mod = (const int*)d_in[1];
  const int*   pos = (const int*)d_in[2];
  const float* Wq  = (const float*)d_in[3];
  const float* Wk0 = (const float*)d_in[4];
  const float* Wk1 = (const float*)d_in[5];
  const float* Wv0 = (const float*)d_in[6];
  const float* Wv1 = (const float*)d_in[7];
  const float* Wo  = (const float*)d_in[8];
  float* out = (float*)d_out;

  u16* p = (u16*)d_ws;
  auto take = [&](size_t n) { u16* r = p; p += n; return r; };
  u16* Xb   = take(16777216);  // X bf16 (4096 x 4096)
  u16* WqT  = take(16777216);  // Wq^T (4096 x 4096)
  u16* WoT  = take(16777216);  // Wo^T
  u16* WkvT = take(16777216);  // [Wk0|Wk1|Wv0|Wv1]^T stacked (4096 x 4096)
  u16* Qr   = take(16777216);  // (b,h,s,d)
  u16* KV4  = take(16777216);  // K0r|K1r|V0r|V1r, each (b,8,s,d)
  // aliases (lifetimes disjoint, stream-ordered):
  u16* Kr  = WqT;               // roped+selected K (b,8,s,d)
  u16* Vtr = WqT + 4194304;     // selected V transposed (b,8,d,s)
  u16* ctx = Xb;                // attention out (b,s,h*128+d)

  k_cvt<<<dim3(16384), 256, 0, stream>>>(X, Xb, 4194304);
  k_tcvt<<<dim3(128, 128), 256, 0, stream>>>(Wq, WqT, 4096, 4096);
  k_tcvt<<<dim3(32, 128), 256, 0, stream>>>(Wk0, WkvT,               4096, 1024);
  k_tcvt<<<dim3(32, 128), 256, 0, stream>>>(Wk1, WkvT + 1 * 4194304, 4096, 1024);
  k_tcvt<<<dim3(32, 128), 256, 0, stream>>>(Wv0, WkvT + 2 * 4194304, 4096, 1024);
  k_tcvt<<<dim3(32, 128), 256, 0, stream>>>(Wv1, WkvT + 3 * 4194304, 4096, 1024);
  k_tcvt<<<dim3(128, 128), 256, 0, stream>>>(Wo, WoT, 4096, 4096);

  k_gemm<1><<<dim3(32, 32), 256, 0, stream>>>(Xb, WqT,  (void*)Qr,  4096, 4096, 4096, 32);
  k_gemm<3><<<dim3(32, 32), 256, 0, stream>>>(Xb, WkvT, (void*)KV4, 4096, 4096, 4096, 8);

  k_ropeq<<<dim3(32768), 256, 0, stream>>>(Qr, pos);
  k_kvprep<<<dim3(512), 256, 0, stream>>>(KV4, KV4 + 4194304, KV4 + 2 * 4194304,
                                          KV4 + 3 * 4194304, mod, pos, Kr, Vtr);

  k_attn<<<dim3(16, 64), 256, 0, stream>>>(Qr, Kr, Vtr, ctx);

  k_gemm<2><<<dim3(32, 32), 256, 0, stream>>>(ctx, WoT, (void*)out, 4096, 4096, 4096, 0);
}

// Round 4
// 667.304 us; speedup vs baseline: 1.7713x; 1.3798x over previous
//
#include <hip/hip_runtime.h>

typedef unsigned short u16;
typedef unsigned int   u32;
using bf16x8 = __attribute__((ext_vector_type(8))) __bf16;
using f32x4  = __attribute__((ext_vector_type(4))) float;

// B=2, S=2048, D=4096, H=32, KV=8, HD=128 hardcoded throughout.

__device__ __forceinline__ u16 f2bf(float f) {
  u32 u = __builtin_bit_cast(u32, f);
  return (u16)((u + 0x7fffu + ((u >> 16) & 1u)) >> 16);
}
__device__ __forceinline__ float bf2f(u16 h) {
  return __builtin_bit_cast(float, (u32)h << 16);
}
__device__ __forceinline__ f32x4 mfma16(bf16x8 a, bf16x8 b, f32x4 c) {
  return __builtin_amdgcn_mfma_f32_16x16x32_bf16(a, b, c, 0, 0, 0);
}
__device__ __forceinline__ void g2l16(const void* gp, void* lp) {
  __builtin_amdgcn_global_load_lds(
      (__attribute__((address_space(1))) void*)(void*)gp,
      (__attribute__((address_space(3))) void*)lp, 16, 0, 0);
}

// ---------------- fp32 -> bf16 elementwise ----------------
__global__ void k_cvt(const float* __restrict__ in, u16* __restrict__ out, int n4) {
  int i = blockIdx.x * 256 + threadIdx.x;
  if (i >= n4) return;
  float4 v = ((const float4*)in)[i];
  ushort4 o;
  o.x = f2bf(v.x); o.y = f2bf(v.y); o.z = f2bf(v.z); o.w = f2bf(v.w);
  ((ushort4*)out)[i] = o;
}

// ---------------- fp32 (K,N) -> bf16 (N,K) transpose-convert ----------------
__global__ void k_tcvt(const float* __restrict__ in, u16* __restrict__ out, int K, int N) {
  __shared__ u16 t[32][33];
  int n0 = blockIdx.x * 32, k0 = blockIdx.y * 32;
  int r = threadIdx.x >> 3, c4 = (threadIdx.x & 7) * 4;
  float4 v = *(const float4*)(in + (size_t)(k0 + r) * N + n0 + c4);
  t[c4 + 0][r] = f2bf(v.x);
  t[c4 + 1][r] = f2bf(v.y);
  t[c4 + 2][r] = f2bf(v.z);
  t[c4 + 3][r] = f2bf(v.w);
  __syncthreads();
  ushort4 o;
  o.x = t[r][c4 + 0]; o.y = t[r][c4 + 1]; o.z = t[r][c4 + 2]; o.w = t[r][c4 + 3];
  *(ushort4*)(out + (size_t)(n0 + r) * K + k0 + c4) = o;
}

// ================= 256x256 deep-pipelined bf16 GEMM (K=N=4096) =================
// A: (M,4096) bf16 row-major.  Bt: (4096,4096) bf16 row-major (pre-transposed).
// 512 threads = 8 waves (2M x 4N), per-wave output 128x64, acc[8][4].
// BK=32 sub-tiles; 4 LDS slots (A 16KB + B 16KB each) = 128KB; staging runs
// 3 tiles ahead -> every tile-top wait is a counted vmcnt(8) (never 0 in the
// main loop). 2 phases x 16 MFMA per tile with setprio; raw s_barrier only.
// LDS addressing: phys slot = g ^ ((row>>1)&3) applied on BOTH sides
// (pre-permuted global source feeding linear global_load_lds dest + permuted
// ds_read) -> ds_read footprint is a full contiguous 1KB region = bank floor.
// MODE 1: bf16 out relayout (b,NH,s,d); MODE 2: fp32 row-major; MODE 3: bf16
// 4-way split (K0|K1|V0|V1), each (b,8,s,d).
#define TILE_BODY(T, VMLIT, DOSTAGE)                                         \
  {                                                                          \
    asm volatile("s_waitcnt vmcnt(" VMLIT ")" ::: "memory");                 \
    __builtin_amdgcn_s_barrier();                                            \
    __builtin_amdgcn_sched_barrier(0);                                       \
    const u16* base_ = lds + ((T) & 3) * 16384;                              \
    bf16x8 bfr[4], afr[4];                                                   \
    _Pragma("unroll")                                                        \
    for (int nf = 0; nf < 4; ++nf)                                           \
      bfr[nf] = *(const bf16x8*)(base_ + boff + nf * 512);                   \
    _Pragma("unroll")                                                        \
    for (int mf = 0; mf < 4; ++mf)                                           \
      afr[mf] = *(const bf16x8*)(base_ + aoff + mf * 512);                   \
    if (DOSTAGE) stage((T) + 3);                                             \
    __builtin_amdgcn_s_setprio(1);                                           \
    _Pragma("unroll")                                                        \
    for (int mf = 0; mf < 4; ++mf)                                           \
      _Pragma("unroll")                                                      \
      for (int nf = 0; nf < 4; ++nf)                                         \
        acc[mf][nf] = mfma16(afr[mf], bfr[nf], acc[mf][nf]);                 \
    __builtin_amdgcn_s_setprio(0);                                           \
    _Pragma("unroll")                                                        \
    for (int mf = 0; mf < 4; ++mf)                                           \
      afr[mf] = *(const bf16x8*)(base_ + aoff + (mf + 4) * 512);             \
    __builtin_amdgcn_s_setprio(1);                                           \
    _Pragma("unroll")                                                        \
    for (int mf = 0; mf < 4; ++mf)                                           \
      _Pragma("unroll")                                                      \
      for (int nf = 0; nf < 4; ++nf)                                         \
        acc[mf + 4][nf] = mfma16(afr[mf], bfr[nf], acc[mf + 4][nf]);         \
    __builtin_amdgcn_s_setprio(0);                                           \
  }

template <int MODE>
__global__ __launch_bounds__(512, 2) void k_gemm8(const u16* __restrict__ A, const u16* __restrict__ Bt,
                                                  void* __restrict__ Cp, int NH) {
  __shared__ u16 lds[4 * 16384];  // 128 KB: slot = A-sub 8192 u16 + B-sub 8192 u16
  const int tid = threadIdx.x, wid = tid >> 6, l = tid & 63, g = l >> 4, li = l & 15;
  const int wr = wid >> 2, wc = wid & 3;  // 2M x 4N wave grid
  // XCD-bijective block swizzle (grid 256, 256%8==0)
  const int bid = blockIdx.x;
  const int swz = (bid & 7) * 32 + (bid >> 3);
  const int m0 = (swz >> 4) * 256, n0 = (swz & 15) * 256;

  // ---- staging source (pre-permuted so linear LDS dest holds permuted data) ----
  const int bo = wid * 2048 + l * 16;                 // chunk i=0 byte offset in 16KB sub-tile
  const int srow = bo >> 6;                           // sub-tile row (64B rows)
  const int sgg = (l & 3) ^ ((l >> 3) & 3);           // logical k-chunk for this phys slot
  const u16* ApA = A + (size_t)(m0 + srow) * 4096 + sgg * 8;
  const u16* ApB = Bt + (size_t)(n0 + srow) * 4096 + sgg * 8;

  auto stage = [&](int t) {
    const u16* a = ApA + t * 32;
    const u16* b = ApB + t * 32;
    u16* da = (u16*)lds + (t & 3) * 16384 + wid * 1024;  // wave-uniform dest (HW adds lane*16B)
    u16* db = da + 8192;
    g2l16(a, da);
    g2l16(a + (size_t)16 * 4096, da + 512);
    g2l16(b, db);
    g2l16(b + (size_t)16 * 4096, db + 512);
  };

  // ---- ds_read lane bases (phys slot = g ^ ((li>>1)&3); row terms are 0 mod 4 after >>1) ----
  const int lsl8 = (g ^ ((li >> 1) & 3)) * 8;
  const int aoff = (wr * 128 + li) * 32 + lsl8;        // + mf*512
  const int boff = 8192 + (wc * 64 + li) * 32 + lsl8;  // + nf*512

  const f32x4 vzero = {0.f, 0.f, 0.f, 0.f};
  f32x4 acc[8][4];
#pragma unroll
  for (int m = 0; m < 8; ++m)
#pragma unroll
    for (int n = 0; n < 4; ++n) acc[m][n] = vzero;

  stage(0); stage(1); stage(2);
  for (int t = 0; t < 125; ++t) TILE_BODY(t, "8", true);
  TILE_BODY(125, "8", false);
  TILE_BODY(126, "4", false);
  TILE_BODY(127, "0", false);

  (void)NH;
#pragma unroll
  for (int mf = 0; mf < 8; ++mf)
#pragma unroll
    for (int nf = 0; nf < 4; ++nf)
#pragma unroll
      for (int j = 0; j < 4; ++j) {
        int row = m0 + wr * 128 + mf * 16 + g * 4 + j;  // C/D: row=(l>>4)*4+reg
        int col = n0 + wc * 64 + nf * 16 + li;          //      col=l&15
        float v = acc[mf][nf][j];
        if constexpr (MODE == 2) {
          ((float*)Cp)[(size_t)row * 4096 + col] = v;
        } else if constexpr (MODE == 1) {
          int b = row >> 11, s = row & 2047, h = col >> 7, d = col & 127;
          ((u16*)Cp)[(((size_t)(b * NH + h)) * 2048 + s) * 128 + d] = f2bf(v);
        } else {
          int b = row >> 11, s = row & 2047;
          int buf = col >> 10, hh = (col >> 7) & 7, d = col & 127;
          ((u16*)Cp)[(size_t)buf * 4194304 + (((size_t)(b * 8 + hh)) * 2048 + s) * 128 + d] = f2bf(v);
        }
      }
}

// ---------------- RoPE on Q in place, fused 1/sqrt(128) scale ----------------
// Qr layout (b,h,s,d); one wave per row; lane l handles pair (d=l, d=l+64).
__global__ void k_ropeq(u16* __restrict__ Q, const int* __restrict__ pos) {
  int row = blockIdx.x * 4 + (threadIdx.x >> 6);
  int l = threadIdx.x & 63;
  int s = row & 2047;
  u16* p = Q + (size_t)row * 128;
  float x1 = bf2f(p[l]), x2 = bf2f(p[l + 64]);
  float ang = (float)pos[s] * expf((float)l * -0.14391156831212787f);  // ln(1e4)/64
  float cs = cosf(ang), sn = sinf(ang);
  const float sc = 0.08838834764831845f;  // 1/sqrt(128)
  p[l] = f2bf((x1 * cs - x2 * sn) * sc);
  p[l + 64] = f2bf((x2 * cs + x1 * sn) * sc);
}

// ---------------- K/V: modality select + RoPE(K) + V transpose to (d,s) ----------------
// block = (b, kv, 64-token tile); K0..V1 are (b,8,s,d) bf16.
__global__ void k_kvprep(const u16* __restrict__ K0, const u16* __restrict__ K1,
                         const u16* __restrict__ V0, const u16* __restrict__ V1,
                         const int* __restrict__ mod, const int* __restrict__ pos,
                         u16* __restrict__ Kr, u16* __restrict__ Vt) {
  __shared__ u16 Vl[64][136];
  int blk = blockIdx.x;
  int st = blk & 31, kvh = (blk >> 5) & 7, b = blk >> 8;
  int s0 = st * 64;
  int tid = threadIdx.x, wid = tid >> 6, l = tid & 63;
  float invf = expf((float)l * -0.14391156831212787f);
  size_t slab = (size_t)(b * 8 + kvh) * 2048;
  for (int rr = 0; rr < 16; ++rr) {
    int r = wid * 16 + rr;
    int s = s0 + r;
    int sel = mod[b * 2048 + s];
    const u16* ks = (sel ? K1 : K0) + (slab + s) * 128;
    const u16* vs = (sel ? V1 : V0) + (slab + s) * 128;
    float ang = (float)pos[s] * invf;
    float cs = cosf(ang), sn = sinf(ang);
    float x1 = bf2f(ks[l]), x2 = bf2f(ks[l + 64]);
    u16* kd = Kr + (slab + s) * 128;
    kd[l] = f2bf(x1 * cs - x2 * sn);
    kd[l + 64] = f2bf(x2 * cs + x1 * sn);
    Vl[r][l] = vs[l];
    Vl[r][l + 64] = vs[l + 64];
  }
  __syncthreads();
  int d = tid >> 1, si0 = (tid & 1) * 32;
  u16* vd = Vt + ((size_t)(b * 8 + kvh) * 128 + d) * 2048 + s0 + si0;
#pragma unroll
  for (int k4 = 0; k4 < 8; ++k4) {
    ushort4 o;
    o.x = Vl[si0 + k4 * 4 + 0][d];
    o.y = Vl[si0 + k4 * 4 + 1][d];
    o.z = Vl[si0 + k4 * 4 + 2][d];
    o.w = Vl[si0 + k4 * 4 + 3][d];
    *(ushort4*)(vd + k4 * 4) = o;
  }
}

// ---------------- causal GQA flash attention (double-buffered, pair-fused) ----------------
#define COMPUTE_HALF(KT, QT, QF, O, MR, LS)                                    \
  {                                                                            \
    f32x4 sf[4];                                                               \
    sf[0] = vzero; sf[1] = vzero; sf[2] = vzero; sf[3] = vzero;                \
    _Pragma("unroll")                                                          \
    for (int ks = 0; ks < 4; ++ks) {                                           \
      bf16x8 kf[4];                                                            \
      _Pragma("unroll")                                                        \
      for (int cf = 0; cf < 4; ++cf) {                                         \
        int krow = cf * 16 + li;                                               \
        int koff = (krow * 256 + ks * 64 + g * 16) ^ ((krow & 7) << 4);        \
        kf[cf] = *(const bf16x8*)(kbase + koff);                               \
      }                                                                        \
      __builtin_amdgcn_s_setprio(1);                                           \
      _Pragma("unroll")                                                        \
      for (int cf = 0; cf < 4; ++cf) sf[cf] = mfma16(QF[ks], kf[cf], sf[cf]);  \
      __builtin_amdgcn_s_setprio(0);                                           \
    }                                                                          \
    if ((KT) == (QT)) {                                                        \
      _Pragma("unroll")                                                        \
      for (int cf = 0; cf < 4; ++cf)                                           \
        _Pragma("unroll")                                                      \
        for (int j = 0; j < 4; ++j)                                            \
          if (cf * 16 + li > wid * 16 + g * 4 + j) sf[cf][j] = -1e30f;         \
    }                                                                          \
    float resc[4];                                                             \
    _Pragma("unroll")                                                          \
    for (int j = 0; j < 4; ++j) {                                              \
      float mx = fmaxf(fmaxf(sf[0][j], sf[1][j]), fmaxf(sf[2][j], sf[3][j])); \
      _Pragma("unroll")                                                        \
      for (int dl = 1; dl < 16; dl <<= 1) mx = fmaxf(mx, __shfl_xor(mx, dl)); \
      float nm = fmaxf(MR[j], mx);                                             \
      resc[j] = exp2f((MR[j] - nm) * 1.4426950408889634f);                     \
      MR[j] = nm;                                                              \
      float rs = 0.f;                                                          \
      _Pragma("unroll")                                                        \
      for (int cf = 0; cf < 4; ++cf) {                                         \
        float pv = exp2f((sf[cf][j] - nm) * 1.4426950408889634f);              \
        sf[cf][j] = pv;                                                        \
        rs += pv;                                                              \
      }                                                                        \
      _Pragma("unroll")                                                        \
      for (int dl = 1; dl < 16; dl <<= 1) rs += __shfl_xor(rs, dl);            \
      LS[j] = LS[j] * resc[j] + rs;                                            \
    }                                                                          \
    _Pragma("unroll")                                                          \
    for (int db = 0; db < 8; ++db)                                             \
      _Pragma("unroll")                                                        \
      for (int j = 0; j < 4; ++j) O[db][j] *= resc[j];                         \
    _Pragma("unroll")                                                          \
    for (int cf = 0; cf < 4; ++cf)                                             \
      _Pragma("unroll")                                                        \
      for (int j = 0; j < 4; ++j)                                              \
        Pw[(g * 4 + j) * 68 + cf * 16 + li] = (__bf16)sf[cf][j];               \
    _Pragma("unroll")                                                          \
    for (int ks = 0; ks < 2; ++ks) {                                           \
      bf16x8 pa = *(const bf16x8*)(Pw + li * 68 + ks * 32 + g * 8);            \
      bf16x8 vf[8];                                                            \
      _Pragma("unroll")                                                        \
      for (int db = 0; db < 8; ++db) {                                         \
        int vrow = db * 16 + li;                                               \
        int voff = (vrow * 128 + ks * 64 + g * 16) ^ ((vrow & 7) << 4);        \
        vf[db] = *(const bf16x8*)(vbase + voff);                               \
      }                                                                        \
      __builtin_amdgcn_s_setprio(1);                                           \
      _Pragma("unroll")                                                        \
      for (int db = 0; db < 8; ++db) O[db] = mfma16(pa, vf[db], O[db]);        \
      __builtin_amdgcn_s_setprio(0);                                           \
    }                                                                          \
  }

__global__ __launch_bounds__(256, 2) void k_attn(const u16* __restrict__ Q, const u16* __restrict__ Kr,
                                                 const u16* __restrict__ Vt, u16* __restrict__ ctx) {
  __shared__ u16 Kl[2 * 64 * 128];
  __shared__ u16 Vl[2 * 128 * 64];
  __shared__ __bf16 Pl[4][16 * 68];
  const int pair = blockIdx.x, bh = blockIdx.y;
  const int b = bh >> 5, h = bh & 31, kvh = h >> 2;
  const int tid = threadIdx.x, wid = tid >> 6, l = tid & 63, g = l >> 4, li = l & 15;
  const int qtA = pair, qtB = 31 - pair;
  const size_t kvslab = (size_t)(b * 8 + kvh) * 2048;
  const u16* Kg = Kr + kvslab * 128;
  const u16* Vg = Vt + kvslab * 128;  // (d, s) layout
  __bf16* Pw = &Pl[wid][0];

  auto stage = [&](int kt, int bi) {
#pragma unroll
    for (int i = 0; i < 4; ++i) {
      int c = wid * 4 + i;
      int slot = c * 1024 + l * 16;
      {  // K tile: 64 rows x 256B
        int row = slot >> 8;
        int inner = (slot & 255) ^ ((row & 7) << 4);
        g2l16((const char*)Kg + kt * 16384 + row * 256 + inner,
              (char*)Kl + bi * 16384 + c * 1024);
      }
      {  // V tile: 128 rows x 128B (rows = d, cols = s-slice of 64 tokens)
        int row = slot >> 7;
        int inner = (slot & 127) ^ ((row & 7) << 4);
        g2l16((const char*)Vg + (size_t)row * 4096 + kt * 128 + inner,
              (char*)Vl + bi * 16384 + c * 1024);
      }
    }
  };

  const u16* qrowA = Q + ((size_t)bh * 2048 + qtA * 64 + wid * 16 + li) * 128;
  const u16* qrowB = Q + ((size_t)bh * 2048 + qtB * 64 + wid * 16 + li) * 128;
  bf16x8 qfA[4], qfB[4];
#pragma unroll
  for (int ks = 0; ks < 4; ++ks) {
    qfA[ks] = *(const bf16x8*)(qrowA + ks * 32 + g * 8);
    qfB[ks] = *(const bf16x8*)(qrowB + ks * 32 + g * 8);
  }
  const f32x4 vzero = {0.f, 0.f, 0.f, 0.f};
  f32x4 oA[8], oB[8];
#pragma unroll
  for (int i = 0; i < 8; ++i) { oA[i] = vzero; oB[i] = vzero; }
  float mA[4] = {-1e30f, -1e30f, -1e30f, -1e30f};
  float mB[4] = {-1e30f, -1e30f, -1e30f, -1e30f};
  float lA[4] = {0.f, 0.f, 0.f, 0.f};
  float lB[4] = {0.f, 0.f, 0.f, 0.f};

  stage(0, 0);
  __syncthreads();
  int cur = 0;
  for (int kt = 0; kt <= qtB; ++kt) {
    if (kt < qtB) stage(kt + 1, cur ^ 1);  // issue next-tile loads FIRST
    const char* kbase = (const char*)Kl + cur * 16384;
    const char* vbase = (const char*)Vl + cur * 16384;
    if (kt <= qtA) COMPUTE_HALF(kt, qtA, qfA, oA, mA, lA);
    COMPUTE_HALF(kt, qtB, qfB, oB, mB, lB);
    __syncthreads();  // drains vmcnt(0): next tile resident, this buf free
    cur ^= 1;
  }

#pragma unroll
  for (int half = 0; half < 2; ++half) {
    const int q0 = (half ? qtB : qtA) * 64;
    f32x4* o = half ? oB : oA;
    float* ls = half ? lB : lA;
    float inv[4];
#pragma unroll
    for (int j = 0; j < 4; ++j) inv[j] = 1.0f / ls[j];
#pragma unroll
    for (int db = 0; db < 8; ++db)
#pragma unroll
      for (int j = 0; j < 4; ++j) {
        int row = q0 + wid * 16 + g * 4 + j;
        ctx[((size_t)(b * 2048) + row) * 4096 + h * 128 + db * 16 + li] = f2bf(o[db][j] * inv[j]);
      }
  }
}

extern "C" void kernel_launch(void* const* d_in, const int* in_sizes, int n_in,
                              void* d_out, int out_size, void* d_ws, size_t ws_size,
                              hipStream_t stream) {
  (void)in_sizes; (void)n_in; (void)out_size; (void)ws_size;
  const float* X   = (const float*)d_in[0];
  const int*   mod = (const int*)d_in[1];
  const int*   pos = (const int*)d_in[2];
  const float* Wq  = (const float*)d_in[3];
  const float* Wk0 = (const float*)d_in[4];
  const float* Wk1 = (const float*)d_in[5];
  const float* Wv0 = (const float*)d_in[6];
  const float* Wv1 = (const float*)d_in[7];
  const float* Wo  = (const float*)d_in[8];
  float* out = (float*)d_out;

  u16* p = (u16*)d_ws;
  auto take = [&](size_t n) { u16* r = p; p += n; return r; };
  u16* Xb   = take(16777216);  // X bf16 (4096 x 4096)
  u16* WqT  = take(16777216);  // Wq^T (4096 x 4096)
  u16* WoT  = take(16777216);  // Wo^T
  u16* WkvT = take(16777216);  // [Wk0|Wk1|Wv0|Wv1]^T stacked (4096 x 4096)
  u16* Qr   = take(16777216);  // (b,h,s,d)
  u16* KV4  = take(16777216);  // K0r|K1r|V0r|V1r, each (b,8,s,d)
  // aliases (lifetimes disjoint, stream-ordered):
  u16* Kr  = WqT;               // roped+selected K (b,8,s,d)
  u16* Vtr = WqT + 4194304;     // selected V transposed (b,8,d,s)
  u16* ctx = Xb;                // attention out (b,s,h*128+d)

  k_cvt<<<dim3(16384), 256, 0, stream>>>(X, Xb, 4194304);
  k_tcvt<<<dim3(128, 128), 256, 0, stream>>>(Wq, WqT, 4096, 4096);
  k_tcvt<<<dim3(32, 128), 256, 0, stream>>>(Wk0, WkvT,               4096, 1024);
  k_tcvt<<<dim3(32, 128), 256, 0, stream>>>(Wk1, WkvT + 1 * 4194304, 4096, 1024);
  k_tcvt<<<dim3(32, 128), 256, 0, stream>>>(Wv0, WkvT + 2 * 4194304, 4096, 1024);
  k_tcvt<<<dim3(32, 128), 256, 0, stream>>>(Wv1, WkvT + 3 * 4194304, 4096, 1024);
  k_tcvt<<<dim3(128, 128), 256, 0, stream>>>(Wo, WoT, 4096, 4096);

  k_gemm8<1><<<dim3(256), 512, 0, stream>>>(Xb, WqT,  (void*)Qr,  32);
  k_gemm8<3><<<dim3(256), 512, 0, stream>>>(Xb, WkvT, (void*)KV4, 8);

  k_ropeq<<<dim3(32768), 256, 0, stream>>>(Qr, pos);
  k_kvprep<<<dim3(512), 256, 0, stream>>>(KV4, KV4 + 4194304, KV4 + 2 * 4194304,
                                          KV4 + 3 * 4194304, mod, pos, Kr, Vtr);

  k_attn<<<dim3(16, 64), 256, 0, stream>>>(Qr, Kr, Vtr, ctx);

  k_gemm8<2><<<dim3(256), 512, 0, stream>>>(ctx, WoT, (void*)out, 0);
}

// Round 5
// 581.519 us; speedup vs baseline: 2.0326x; 1.1475x over previous
//
#include <hip/hip_runtime.h>

typedef unsigned short u16;
typedef unsigned int   u32;
using bf16x8 = __attribute__((ext_vector_type(8))) __bf16;
using f32x4  = __attribute__((ext_vector_type(4))) float;
using f32x16 = __attribute__((ext_vector_type(16))) float;
using u32x4  = __attribute__((ext_vector_type(4))) unsigned int;

// B=2, S=2048, D=4096, H=32, KV=8, HD=128 hardcoded throughout.

__device__ __forceinline__ u16 f2bf(float f) {
  u32 u = __builtin_bit_cast(u32, f);
  return (u16)((u + 0x7fffu + ((u >> 16) & 1u)) >> 16);
}
__device__ __forceinline__ float bf2f(u16 h) {
  return __builtin_bit_cast(float, (u32)h << 16);
}
__device__ __forceinline__ f32x4 mfma16(bf16x8 a, bf16x8 b, f32x4 c) {
  return __builtin_amdgcn_mfma_f32_16x16x32_bf16(a, b, c, 0, 0, 0);
}
__device__ __forceinline__ f32x16 mfma32(bf16x8 a, bf16x8 b, f32x16 c) {
  return __builtin_amdgcn_mfma_f32_32x32x16_bf16(a, b, c, 0, 0, 0);
}
__device__ __forceinline__ f32x16 zero16() {
  f32x16 z;
#pragma unroll
  for (int i = 0; i < 16; ++i) z[i] = 0.f;
  return z;
}
__device__ __forceinline__ void g2l16(const void* gp, void* lp) {
  __builtin_amdgcn_global_load_lds(
      (__attribute__((address_space(1))) void*)(void*)gp,
      (__attribute__((address_space(3))) void*)lp, 16, 0, 0);
}

// ---------------- fp32 -> bf16 elementwise ----------------
__global__ void k_cvt(const float* __restrict__ in, u16* __restrict__ out, int n4) {
  int i = blockIdx.x * 256 + threadIdx.x;
  if (i >= n4) return;
  float4 v = ((const float4*)in)[i];
  ushort4 o;
  o.x = f2bf(v.x); o.y = f2bf(v.y); o.z = f2bf(v.z); o.w = f2bf(v.w);
  ((ushort4*)out)[i] = o;
}

// ---------------- fp32 (K,N) -> bf16 (N,K) transpose-convert ----------------
__global__ void k_tcvt(const float* __restrict__ in, u16* __restrict__ out, int K, int N) {
  __shared__ u16 t[32][33];
  int n0 = blockIdx.x * 32, k0 = blockIdx.y * 32;
  int r = threadIdx.x >> 3, c4 = (threadIdx.x & 7) * 4;
  float4 v = *(const float4*)(in + (size_t)(k0 + r) * N + n0 + c4);
  t[c4 + 0][r] = f2bf(v.x);
  t[c4 + 1][r] = f2bf(v.y);
  t[c4 + 2][r] = f2bf(v.z);
  t[c4 + 3][r] = f2bf(v.w);
  __syncthreads();
  ushort4 o;
  o.x = t[r][c4 + 0]; o.y = t[r][c4 + 1]; o.z = t[r][c4 + 2]; o.w = t[r][c4 + 3];
  *(ushort4*)(out + (size_t)(n0 + r) * K + k0 + c4) = o;
}

// ================= 256x256 deep-pipelined bf16 GEMM (K=N=4096) =================
#define TILE_BODY(T, VMLIT, DOSTAGE)                                         \
  {                                                                          \
    asm volatile("s_waitcnt vmcnt(" VMLIT ")" ::: "memory");                 \
    __builtin_amdgcn_s_barrier();                                            \
    __builtin_amdgcn_sched_barrier(0);                                       \
    const u16* base_ = lds + ((T) & 3) * 16384;                              \
    bf16x8 bfr[4], afr[4];                                                   \
    _Pragma("unroll")                                                        \
    for (int nf = 0; nf < 4; ++nf)                                           \
      bfr[nf] = *(const bf16x8*)(base_ + boff + nf * 512);                   \
    _Pragma("unroll")                                                        \
    for (int mf = 0; mf < 4; ++mf)                                           \
      afr[mf] = *(const bf16x8*)(base_ + aoff + mf * 512);                   \
    if (DOSTAGE) stage((T) + 3);                                             \
    __builtin_amdgcn_s_setprio(1);                                           \
    _Pragma("unroll")                                                        \
    for (int mf = 0; mf < 4; ++mf)                                           \
      _Pragma("unroll")                                                      \
      for (int nf = 0; nf < 4; ++nf)                                         \
        acc[mf][nf] = mfma16(afr[mf], bfr[nf], acc[mf][nf]);                 \
    __builtin_amdgcn_s_setprio(0);                                           \
    _Pragma("unroll")                                                        \
    for (int mf = 0; mf < 4; ++mf)                                           \
      afr[mf] = *(const bf16x8*)(base_ + aoff + (mf + 4) * 512);             \
    __builtin_amdgcn_s_setprio(1);                                           \
    _Pragma("unroll")                                                        \
    for (int mf = 0; mf < 4; ++mf)                                           \
      _Pragma("unroll")                                                      \
      for (int nf = 0; nf < 4; ++nf)                                         \
        acc[mf + 4][nf] = mfma16(afr[mf], bfr[nf], acc[mf + 4][nf]);         \
    __builtin_amdgcn_s_setprio(0);                                           \
  }

template <int MODE>
__global__ __launch_bounds__(512, 2) void k_gemm8(const u16* __restrict__ A, const u16* __restrict__ Bt,
                                                  void* __restrict__ Cp, int NH) {
  __shared__ u16 lds[4 * 16384];  // 128 KB
  const int tid = threadIdx.x, wid = tid >> 6, l = tid & 63, g = l >> 4, li = l & 15;
  const int wr = wid >> 2, wc = wid & 3;
  const int bid = blockIdx.x;
  const int swz = (bid & 7) * 32 + (bid >> 3);
  const int m0 = (swz >> 4) * 256, n0 = (swz & 15) * 256;

  const int bo = wid * 2048 + l * 16;
  const int srow = bo >> 6;
  const int sgg = (l & 3) ^ ((l >> 3) & 3);
  const u16* ApA = A + (size_t)(m0 + srow) * 4096 + sgg * 8;
  const u16* ApB = Bt + (size_t)(n0 + srow) * 4096 + sgg * 8;

  auto stage = [&](int t) {
    const u16* a = ApA + t * 32;
    const u16* b = ApB + t * 32;
    u16* da = (u16*)lds + (t & 3) * 16384 + wid * 1024;
    u16* db = da + 8192;
    g2l16(a, da);
    g2l16(a + (size_t)16 * 4096, da + 512);
    g2l16(b, db);
    g2l16(b + (size_t)16 * 4096, db + 512);
  };

  const int lsl8 = (g ^ ((li >> 1) & 3)) * 8;
  const int aoff = (wr * 128 + li) * 32 + lsl8;
  const int boff = 8192 + (wc * 64 + li) * 32 + lsl8;

  const f32x4 vzero = {0.f, 0.f, 0.f, 0.f};
  f32x4 acc[8][4];
#pragma unroll
  for (int m = 0; m < 8; ++m)
#pragma unroll
    for (int n = 0; n < 4; ++n) acc[m][n] = vzero;

  stage(0); stage(1); stage(2);
  for (int t = 0; t < 125; ++t) TILE_BODY(t, "8", true);
  TILE_BODY(125, "8", false);
  TILE_BODY(126, "4", false);
  TILE_BODY(127, "0", false);

  (void)NH;
#pragma unroll
  for (int mf = 0; mf < 8; ++mf)
#pragma unroll
    for (int nf = 0; nf < 4; ++nf)
#pragma unroll
      for (int j = 0; j < 4; ++j) {
        int row = m0 + wr * 128 + mf * 16 + g * 4 + j;
        int col = n0 + wc * 64 + nf * 16 + li;
        float v = acc[mf][nf][j];
        if constexpr (MODE == 2) {
          ((float*)Cp)[(size_t)row * 4096 + col] = v;
        } else if constexpr (MODE == 1) {
          int b = row >> 11, s = row & 2047, h = col >> 7, d = col & 127;
          ((u16*)Cp)[(((size_t)(b * NH + h)) * 2048 + s) * 128 + d] = f2bf(v);
        } else {
          int b = row >> 11, s = row & 2047;
          int buf = col >> 10, hh = (col >> 7) & 7, d = col & 127;
          ((u16*)Cp)[(size_t)buf * 4194304 + (((size_t)(b * 8 + hh)) * 2048 + s) * 128 + d] = f2bf(v);
        }
      }
}

// ---------------- RoPE on Q in place, fused 1/sqrt(128) scale ----------------
__global__ void k_ropeq(u16* __restrict__ Q, const int* __restrict__ pos) {
  int row = blockIdx.x * 4 + (threadIdx.x >> 6);
  int l = threadIdx.x & 63;
  int s = row & 2047;
  u16* p = Q + (size_t)row * 128;
  float x1 = bf2f(p[l]), x2 = bf2f(p[l + 64]);
  float ang = (float)pos[s] * expf((float)l * -0.14391156831212787f);
  float cs = cosf(ang), sn = sinf(ang);
  const float sc = 0.08838834764831845f;
  p[l] = f2bf((x1 * cs - x2 * sn) * sc);
  p[l + 64] = f2bf((x2 * cs + x1 * sn) * sc);
}

// ---------------- K/V: modality select + RoPE(K) + V transpose to (d,s) ----------------
__global__ void k_kvprep(const u16* __restrict__ K0, const u16* __restrict__ K1,
                         const u16* __restrict__ V0, const u16* __restrict__ V1,
                         const int* __restrict__ mod, const int* __restrict__ pos,
                         u16* __restrict__ Kr, u16* __restrict__ Vt) {
  __shared__ u16 Vl[64][136];
  int blk = blockIdx.x;
  int st = blk & 31, kvh = (blk >> 5) & 7, b = blk >> 8;
  int s0 = st * 64;
  int tid = threadIdx.x, wid = tid >> 6, l = tid & 63;
  float invf = expf((float)l * -0.14391156831212787f);
  size_t slab = (size_t)(b * 8 + kvh) * 2048;
  for (int rr = 0; rr < 16; ++rr) {
    int r = wid * 16 + rr;
    int s = s0 + r;
    int sel = mod[b * 2048 + s];
    const u16* ks = (sel ? K1 : K0) + (slab + s) * 128;
    const u16* vs = (sel ? V1 : V0) + (slab + s) * 128;
    float ang = (float)pos[s] * invf;
    float cs = cosf(ang), sn = sinf(ang);
    float x1 = bf2f(ks[l]), x2 = bf2f(ks[l + 64]);
    u16* kd = Kr + (slab + s) * 128;
    kd[l] = f2bf(x1 * cs - x2 * sn);
    kd[l + 64] = f2bf(x2 * cs + x1 * sn);
    Vl[r][l] = vs[l];
    Vl[r][l + 64] = vs[l + 64];
  }
  __syncthreads();
  int d = tid >> 1, si0 = (tid & 1) * 32;
  u16* vd = Vt + ((size_t)(b * 8 + kvh) * 128 + d) * 2048 + s0 + si0;
#pragma unroll
  for (int k4 = 0; k4 < 8; ++k4) {
    ushort4 o;
    o.x = Vl[si0 + k4 * 4 + 0][d];
    o.y = Vl[si0 + k4 * 4 + 1][d];
    o.z = Vl[si0 + k4 * 4 + 2][d];
    o.w = Vl[si0 + k4 * 4 + 3][d];
    *(ushort4*)(vd + k4 * 4) = o;
  }
}

// ---------------- causal GQA flash attention: 32x32 swapped MFMA, in-reg softmax ----------------
// grid (64 bh, 16): qi = 15 - blockIdx.y (long blocks first). Block = 128 q-rows,
// 4 waves x 32 q. KVBLK=64, K/V double-buffered in LDS (64 KB, no P buffer).
// QK^T swapped: S^T = mfma32(A=K_lds, B=Q_regs) -> lane holds 32 k-scores of ONE q
// (softmax = in-reg trees + one shfl_xor(32)). PV swapped: O^T = mfma32(A=V^T_lds,
// B=P^T_regs); P^T B-frags built in-register via v_cvt_pk_bf16_f32 + shfl_xor(32).
// T13 defer-max (THR=8). One vmcnt-drain barrier per kt tile.
__global__ __launch_bounds__(256, 2) void k_attn(const u16* __restrict__ Q, const u16* __restrict__ Kr,
                                                 const u16* __restrict__ Vt, u16* __restrict__ ctx) {
  __shared__ u16 Kl[2 * 64 * 128];
  __shared__ u16 Vl[2 * 128 * 64];
  const int bh = blockIdx.x;
  const int qi = 15 - (int)blockIdx.y;
  const int b = bh >> 5, h = bh & 31, kvh = h >> 2;
  const int tid = threadIdx.x, w = tid >> 6, l = tid & 63;
  const int lo5 = l & 31, hi = l >> 5;
  const bool hib = hi != 0;
  const int q0 = qi * 128;
  const int qlane = q0 + w * 32 + lo5;
  const size_t kvslab = (size_t)(b * 8 + kvh) * 2048;
  const u16* Kg = Kr + kvslab * 128;
  const u16* Vg = Vt + kvslab * 128;  // (d, s) layout

  auto stage = [&](int kt, int bi) {
#pragma unroll
    for (int i = 0; i < 4; ++i) {
      int c = w * 4 + i;
      int slot = c * 1024 + l * 16;
      {  // K tile: 64 rows x 256B, xor-swizzled source (rule #21)
        int row = slot >> 8;
        int inner = (slot & 255) ^ ((row & 7) << 4);
        g2l16((const char*)Kg + kt * 16384 + row * 256 + inner,
              (char*)Kl + bi * 16384 + c * 1024);
      }
      {  // V tile: 128 rows (d) x 128B
        int row = slot >> 7;
        int inner = (slot & 127) ^ ((row & 7) << 4);
        g2l16((const char*)Vg + (size_t)row * 4096 + kt * 128 + inner,
              (char*)Vl + bi * 16384 + c * 1024);
      }
    }
  };

  // Q B-frags: lane -> col(q)=lo5, k(d)=kk*16+hi*8+e
  const u16* qrow = Q + ((size_t)bh * 2048 + qlane) * 128;
  bf16x8 qf[8];
#pragma unroll
  for (int kk = 0; kk < 8; ++kk) qf[kk] = *(const bf16x8*)(qrow + kk * 16 + hi * 8);

  f32x16 ot[4];
#pragma unroll
  for (int i = 0; i < 4; ++i) ot[i] = zero16();
  float m = -1e30f, ls = 0.f;
  const float L2E = 1.4426950408889634f;

  const int nkt = 2 * qi + 2;
  stage(0, 0);
  __syncthreads();
  int cur = 0;
  for (int kt = 0; kt < nkt; ++kt) {
    if (kt + 1 < nkt) stage(kt + 1, cur ^ 1);  // issue next-tile loads first
    const char* kbase = (const char*)Kl + cur * 16384;
    const char* vbase = (const char*)Vl + cur * 16384;
    const int ktb = kt * 64;
    if (ktb <= q0 + w * 32 + 31) {  // wave-uniform active check
      // ---- QK^T swapped: st[mf] = S^T[k=mf*32+..][q] ----
      f32x16 st[2];
      st[0] = zero16(); st[1] = zero16();
#pragma unroll
      for (int kk = 0; kk < 8; ++kk) {
        bf16x8 kfr[2];
#pragma unroll
        for (int mf = 0; mf < 2; ++mf) {
          int row = mf * 32 + lo5;
          kfr[mf] = *(const bf16x8*)(kbase + row * 256 + ((kk * 32 + hi * 16) ^ ((row & 7) << 4)));
        }
        __builtin_amdgcn_s_setprio(1);
        st[0] = mfma32(kfr[0], qf[kk], st[0]);
        st[1] = mfma32(kfr[1], qf[kk], st[1]);
        __builtin_amdgcn_s_setprio(0);
      }
      // ---- causal mask (only boundary tiles) ----
      if (ktb + 63 > q0 + w * 32) {
#pragma unroll
        for (int mf = 0; mf < 2; ++mf)
#pragma unroll
          for (int r = 0; r < 16; ++r) {
            int kg = ktb + mf * 32 + (r & 3) + 8 * (r >> 2) + 4 * hi;
            if (kg > qlane) st[mf][r] = -3.0e38f;
          }
      }
      // ---- online softmax, fully in-register (one shfl for the lane^32 half) ----
      float t[16];
#pragma unroll
      for (int r = 0; r < 16; ++r) t[r] = fmaxf(st[0][r], st[1][r]);
#pragma unroll
      for (int s = 8; s >= 1; s >>= 1)
#pragma unroll
        for (int r = 0; r < s; ++r) t[r] = fmaxf(t[r], t[r + s]);
      float pmax = fmaxf(t[0], __shfl_xor(t[0], 32));
      if (!__all(pmax <= m + 8.f)) {  // T13 defer-max
        float nm = fmaxf(m, pmax);
        float resc = exp2f((m - nm) * L2E);
        m = nm;
        ls *= resc;
#pragma unroll
        for (int i = 0; i < 4; ++i)
#pragma unroll
          for (int r = 0; r < 16; ++r) ot[i][r] *= resc;
      }
#pragma unroll
      for (int mf = 0; mf < 2; ++mf)
#pragma unroll
        for (int r = 0; r < 16; ++r) st[mf][r] = exp2f((st[mf][r] - m) * L2E);
      float u[16];
#pragma unroll
      for (int r = 0; r < 16; ++r) u[r] = st[0][r] + st[1][r];
#pragma unroll
      for (int s = 8; s >= 1; s >>= 1)
#pragma unroll
        for (int r = 0; r < s; ++r) u[r] += u[r + s];
      ls += u[0] + __shfl_xor(u[0], 32);
      // ---- pack P^T -> bf16 B-frags (T12: cvt_pk + lane^32 exchange) ----
      u32 pkv[16];
#pragma unroll
      for (int mf = 0; mf < 2; ++mf)
#pragma unroll
        for (int tt = 0; tt < 8; ++tt) {
          u32 r;
          asm("v_cvt_pk_bf16_f32 %0, %1, %2" : "=v"(r) : "v"(st[mf][2 * tt]), "v"(st[mf][2 * tt + 1]));
          pkv[mf * 8 + tt] = r;
        }
      bf16x8 pfrag[4];
#pragma unroll
      for (int kk = 0; kk < 4; ++kk) {
        int c = (kk >> 1) * 8 + (kk & 1) * 4;
        u32 m0 = hib ? pkv[c + 2] : pkv[c + 0];  // own half (k-offset 4*hi)
        u32 m1 = hib ? pkv[c + 3] : pkv[c + 1];
        u32 s0 = hib ? pkv[c + 0] : pkv[c + 2];  // what partner needs from us
        u32 s1 = hib ? pkv[c + 1] : pkv[c + 3];
        u32 r0 = (u32)__shfl_xor((int)s0, 32);
        u32 r1 = (u32)__shfl_xor((int)s1, 32);
        u32x4 wv = {hib ? r0 : m0, hib ? r1 : m1, hib ? m0 : r0, hib ? m1 : r1};
        pfrag[kk] = __builtin_bit_cast(bf16x8, wv);
      }
      // ---- PV swapped: ot[mfV] += V^T-frag x P^T-frag ----
#pragma unroll
      for (int mfV = 0; mfV < 4; ++mfV) {
        int row = mfV * 32 + lo5;
        const char* vb = vbase + row * 128;
        int sw = (row & 7) << 4;
        bf16x8 vf[4];
#pragma unroll
        for (int kk = 0; kk < 4; ++kk)
          vf[kk] = *(const bf16x8*)(vb + ((kk * 32 + hi * 16) ^ sw));
        __builtin_amdgcn_s_setprio(1);
#pragma unroll
        for (int kk = 0; kk < 4; ++kk) ot[mfV] = mfma32(vf[kk], pfrag[kk], ot[mfV]);
        __builtin_amdgcn_s_setprio(0);
      }
    }
    __syncthreads();  // drains vmcnt(0): next tile resident, this buf free
    cur ^= 1;
  }
  // ---- epilogue: O = (O^T)^T / ls -> ctx (b, s, h*128+d) ----
  float inv = 1.0f / ls;
  u16* crow = ctx + ((size_t)(b * 2048) + qlane) * 4096 + h * 128;
#pragma unroll
  for (int mfV = 0; mfV < 4; ++mfV)
#pragma unroll
    for (int rq = 0; rq < 4; ++rq) {
      ushort4 o4;
      o4.x = f2bf(ot[mfV][rq * 4 + 0] * inv);
      o4.y = f2bf(ot[mfV][rq * 4 + 1] * inv);
      o4.z = f2bf(ot[mfV][rq * 4 + 2] * inv);
      o4.w = f2bf(ot[mfV][rq * 4 + 3] * inv);
      *(ushort4*)(crow + mfV * 32 + rq * 8 + hi * 4) = o4;
    }
}

extern "C" void kernel_launch(void* const* d_in, const int* in_sizes, int n_in,
                              void* d_out, int out_size, void* d_ws, size_t ws_size,
                              hipStream_t stream) {
  (void)in_sizes; (void)n_in; (void)out_size; (void)ws_size;
  const float* X   = (const float*)d_in[0];
  const int*   mod = (const int*)d_in[1];
  const int*   pos = (const int*)d_in[2];
  const float* Wq  = (const float*)d_in[3];
  const float* Wk0 = (const float*)d_in[4];
  const float* Wk1 = (const float*)d_in[5];
  const float* Wv0 = (const float*)d_in[6];
  const float* Wv1 = (const float*)d_in[7];
  const float* Wo  = (const float*)d_in[8];
  float* out = (float*)d_out;

  u16* p = (u16*)d_ws;
  auto take = [&](size_t n) { u16* r = p; p += n; return r; };
  u16* Xb   = take(16777216);
  u16* WqT  = take(16777216);
  u16* WoT  = take(16777216);
  u16* WkvT = take(16777216);
  u16* Qr   = take(16777216);
  u16* KV4  = take(16777216);
  u16* Kr  = WqT;
  u16* Vtr = WqT + 4194304;
  u16* ctx = Xb;

  k_cvt<<<dim3(16384), 256, 0, stream>>>(X, Xb, 4194304);
  k_tcvt<<<dim3(128, 128), 256, 0, stream>>>(Wq, WqT, 4096, 4096);
  k_tcvt<<<dim3(32, 128), 256, 0, stream>>>(Wk0, WkvT,               4096, 1024);
  k_tcvt<<<dim3(32, 128), 256, 0, stream>>>(Wk1, WkvT + 1 * 4194304, 4096, 1024);
  k_tcvt<<<dim3(32, 128), 256, 0, stream>>>(Wv0, WkvT + 2 * 4194304, 4096, 1024);
  k_tcvt<<<dim3(32, 128), 256, 0, stream>>>(Wv1, WkvT + 3 * 4194304, 4096, 1024);
  k_tcvt<<<dim3(128, 128), 256, 0, stream>>>(Wo, WoT, 4096, 4096);

  k_gemm8<1><<<dim3(256), 512, 0, stream>>>(Xb, WqT,  (void*)Qr,  32);
  k_gemm8<3><<<dim3(256), 512, 0, stream>>>(Xb, WkvT, (void*)KV4, 8);

  k_ropeq<<<dim3(32768), 256, 0, stream>>>(Qr, pos);
  k_kvprep<<<dim3(512), 256, 0, stream>>>(KV4, KV4 + 4194304, KV4 + 2 * 4194304,
                                          KV4 + 3 * 4194304, mod, pos, Kr, Vtr);

  k_attn<<<dim3(64, 16), 256, 0, stream>>>(Qr, Kr, Vtr, ctx);

  k_gemm8<2><<<dim3(256), 512, 0, stream>>>(ctx, WoT, (void*)out, 0);
}